// Round 4
// baseline (29626.923 us; speedup 1.0000x reference)
//
#include <hip/hip_runtime.h>
#include <stdint.h>

#define Bn 4
#define Ln 2048
#define Dn 1024
#define Hn 16
#define DHn 64

typedef unsigned long long u64;

// ---------------- fp32 GEMM: C[M,N] = (X[M,K] @ W[K,N] + bias[N]) * scale ----------------
// BM=BN=64, BK=16, 256 threads, 4x4 micro-tile. W read natively [k][n] (no transpose).
__global__ __launch_bounds__(256) void gemm_f32(
    const float* __restrict__ X, const float* __restrict__ W,
    const float* __restrict__ bias, float* __restrict__ C,
    int M, int N, int K, float scale)
{
  __shared__ float ldsA[16][65];   // [k][m]
  __shared__ float ldsB[16][65];   // [k][n]
  const int t = threadIdx.x;
  const int m0 = blockIdx.y * 64, n0 = blockIdx.x * 64;
  const int tm = (t >> 4) * 4, tn = (t & 15) * 4;

  float acc[4][4] = {{0.f}};

  for (int k0 = 0; k0 < K; k0 += 16) {
    float4 xa = *(const float4*)&X[(size_t)(m0 + (t >> 2)) * K + k0 + (t & 3) * 4];
    float4 wb = *(const float4*)&W[(size_t)(k0 + (t >> 4)) * N + n0 + (t & 15) * 4];
    __syncthreads();
    ldsA[(t & 3) * 4 + 0][t >> 2] = xa.x;
    ldsA[(t & 3) * 4 + 1][t >> 2] = xa.y;
    ldsA[(t & 3) * 4 + 2][t >> 2] = xa.z;
    ldsA[(t & 3) * 4 + 3][t >> 2] = xa.w;
    *(float4*)&ldsB[t >> 4][(t & 15) * 4] = wb;
    __syncthreads();
    #pragma unroll
    for (int kk = 0; kk < 16; ++kk) {
      float4 a4 = *(float4*)&ldsA[kk][tm];
      float4 b4 = *(float4*)&ldsB[kk][tn];
      float a[4] = {a4.x, a4.y, a4.z, a4.w};
      float b[4] = {b4.x, b4.y, b4.z, b4.w};
      #pragma unroll
      for (int i = 0; i < 4; ++i)
        #pragma unroll
        for (int j = 0; j < 4; ++j)
          acc[i][j] = fmaf(a[i], b[j], acc[i][j]);
    }
  }

  float4 bv = *(const float4*)&bias[n0 + tn];
  float bb[4] = {bv.x, bv.y, bv.z, bv.w};
  #pragma unroll
  for (int i = 0; i < 4; ++i) {
    float4 o;
    o.x = (acc[i][0] + bb[0]) * scale;
    o.y = (acc[i][1] + bb[1]) * scale;
    o.z = (acc[i][2] + bb[2]) * scale;
    o.w = (acc[i][3] + bb[3]) * scale;
    *(float4*)&C[(size_t)(m0 + tm + i) * N + n0 + tn] = o;
  }
}

// ---------------- pack mask bits: pm word w = bits for elements w*64..w*64+63 ----------------
__global__ __launch_bounds__(256) void pack_mask(const int* __restrict__ mask, u64* __restrict__ pm)
{
  size_t tg = (size_t)blockIdx.x * 256 + threadIdx.x;
  int v = mask[tg];
  u64 bal = __ballot(v != 0);
  if ((threadIdx.x & 63) == 0) pm[tg >> 6] = bal;
}

// ---------------- pass A: stat[bh][q] = (rowmax m, 1/l) with l = sum exp(s-m) over unmasked ----
// 256 thr: q = t>>3 (32 q-rows), g = t&7 handles k = kk*8+g per 128-chunk.
__global__ __launch_bounds__(256) void attn_stat(
    const float* __restrict__ Qb, const float* __restrict__ Kb,
    const u64* __restrict__ pm, float2* __restrict__ stat)
{
  __shared__ float ldsK[128][65];
  const int t = threadIdx.x;
  const int q = t >> 3, g = t & 7;
  const int b = blockIdx.z, h = blockIdx.y, q0 = blockIdx.x * 32;

  const float* qrow = Qb + ((size_t)(b * Ln + q0 + q)) * Dn + h * DHn;
  float4 qreg[16];
  #pragma unroll
  for (int d4 = 0; d4 < 16; ++d4) qreg[d4] = *(const float4*)&qrow[d4 * 4];

  const u64* pmq = pm + ((size_t)(b * Ln + q0 + q)) * 32;

  float mt = -INFINITY, lt = 0.f;

  for (int k0 = 0; k0 < Ln; k0 += 128) {
    __syncthreads();
    #pragma unroll
    for (int jj = 0; jj < 8; ++jj) {
      int idx = jj * 256 + t;
      int row = idx >> 4, c4 = (idx & 15) * 4;
      *(float4*)&ldsK[row][c4] =
          *(const float4*)&Kb[((size_t)(b * Ln + k0 + row)) * Dn + h * DHn + c4];
    }
    __syncthreads();
    u64 w0 = pmq[k0 >> 6], w1 = pmq[(k0 >> 6) + 1];
    #pragma unroll
    for (int kk = 0; kk < 16; ++kk) {
      int k = kk * 8 + g;
      u64 w = (k & 64) ? w1 : w0;
      bool msk = (w >> (k & 63)) & 1ull;
      if (!msk) {
        float s = 0.f;
        #pragma unroll
        for (int d4 = 0; d4 < 16; ++d4) {
          float4 kv = *(float4*)&ldsK[k][d4 * 4];
          s = fmaf(qreg[d4].x, kv.x, s);
          s = fmaf(qreg[d4].y, kv.y, s);
          s = fmaf(qreg[d4].z, kv.z, s);
          s = fmaf(qreg[d4].w, kv.w, s);
        }
        if (s <= mt) {
          lt += __expf(s - mt);
        } else {
          lt = lt * __expf(mt - s) + 1.0f;
          mt = s;
        }
      }
    }
  }
  // merge (m,l) across the 8 g-threads of this q-row (consecutive lanes)
  #pragma unroll
  for (int off = 1; off < 8; off <<= 1) {
    float om = __shfl_xor(mt, off, 64);
    float ol = __shfl_xor(lt, off, 64);
    float nm = fmaxf(mt, om);
    float t1 = (lt > 0.f) ? lt * __expf(mt - nm) : 0.f;
    float t2 = (ol > 0.f) ? ol * __expf(om - nm) : 0.f;
    mt = nm; lt = t1 + t2;
  }
  if (g == 0) {
    float rinv = (lt > 0.f) ? 1.0f / lt : 0.f;
    stat[((size_t)(b * Hn + h)) * Ln + q0 + q] = make_float2(mt, rinv);
  }
}

// ---------------- pass B: ctx = softmax(S) @ V, top_attn for h==0 ----------------
__global__ __launch_bounds__(256) void attn_out(
    const float* __restrict__ Qb, const float* __restrict__ Kb,
    const float* __restrict__ Vb, const u64* __restrict__ pm,
    const float2* __restrict__ stat, float* __restrict__ ctx,
    float* __restrict__ topattn)
{
  __shared__ float ldsK[128][65];
  __shared__ float ldsV[128][65];
  const int t = threadIdx.x;
  const int q = t >> 3, g = t & 7;
  const int b = blockIdx.z, h = blockIdx.y, q0 = blockIdx.x * 32;

  const float* qrow = Qb + ((size_t)(b * Ln + q0 + q)) * Dn + h * DHn;
  float4 qreg[16];
  #pragma unroll
  for (int d4 = 0; d4 < 16; ++d4) qreg[d4] = *(const float4*)&qrow[d4 * 4];

  const u64* pmq = pm + ((size_t)(b * Ln + q0 + q)) * 32;
  float2 st = stat[((size_t)(b * Hn + h)) * Ln + q0 + q];
  const float m = st.x, rinv = st.y;

  float O[64];
  #pragma unroll
  for (int d = 0; d < 64; ++d) O[d] = 0.f;

  for (int k0 = 0; k0 < Ln; k0 += 128) {
    __syncthreads();
    #pragma unroll
    for (int jj = 0; jj < 8; ++jj) {
      int idx = jj * 256 + t;
      int row = idx >> 4, c4 = (idx & 15) * 4;
      size_t gsrc = ((size_t)(b * Ln + k0 + row)) * Dn + h * DHn + c4;
      *(float4*)&ldsK[row][c4] = *(const float4*)&Kb[gsrc];
      *(float4*)&ldsV[row][c4] = *(const float4*)&Vb[gsrc];
    }
    __syncthreads();
    u64 w0 = pmq[k0 >> 6], w1 = pmq[(k0 >> 6) + 1];
    #pragma unroll
    for (int kk = 0; kk < 16; ++kk) {
      int k = kk * 8 + g;
      u64 w = (k & 64) ? w1 : w0;
      bool msk = (w >> (k & 63)) & 1ull;
      float p = 0.f;
      if (!msk) {
        float s = 0.f;
        #pragma unroll
        for (int d4 = 0; d4 < 16; ++d4) {
          float4 kv = *(float4*)&ldsK[k][d4 * 4];
          s = fmaf(qreg[d4].x, kv.x, s);
          s = fmaf(qreg[d4].y, kv.y, s);
          s = fmaf(qreg[d4].z, kv.z, s);
          s = fmaf(qreg[d4].w, kv.w, s);
        }
        p = __expf(s - m) * rinv;   // s <= m always; no overflow
      }
      if (h == 0)
        topattn[((size_t)(b * Ln + q0 + q)) * Ln + k0 + k] = p;
      #pragma unroll
      for (int d4 = 0; d4 < 16; ++d4) {
        float4 vv = *(float4*)&ldsV[k][d4 * 4];
        O[d4 * 4 + 0] = fmaf(p, vv.x, O[d4 * 4 + 0]);
        O[d4 * 4 + 1] = fmaf(p, vv.y, O[d4 * 4 + 1]);
        O[d4 * 4 + 2] = fmaf(p, vv.z, O[d4 * 4 + 2]);
        O[d4 * 4 + 3] = fmaf(p, vv.w, O[d4 * 4 + 3]);
      }
    }
  }
  // butterfly-reduce O over the 8 g-threads; afterwards all lanes hold the sum
  #pragma unroll
  for (int off = 1; off < 8; off <<= 1)
    #pragma unroll
    for (int d = 0; d < 64; ++d)
      O[d] += __shfl_xor(O[d], off, 64);

  // lane g writes d in [g*8, g*8+8) with compile-time indices
  float* crow = ctx + ((size_t)(b * Ln + q0 + q)) * Dn + h * DHn;
  #pragma unroll
  for (int dd = 0; dd < 16; ++dd) {
    if ((dd >> 1) == g) {
      float4 o;
      o.x = O[dd * 4 + 0]; o.y = O[dd * 4 + 1];
      o.z = O[dd * 4 + 2]; o.w = O[dd * 4 + 3];
      *(float4*)&crow[dd * 4] = o;
    }
  }
}

extern "C" void kernel_launch(void* const* d_in, const int* in_sizes, int n_in,
                              void* d_out, int out_size, void* d_ws, size_t ws_size,
                              hipStream_t stream) {
  (void)in_sizes; (void)n_in; (void)out_size; (void)ws_size;
  const float* key   = (const float*)d_in[0];
  const float* value = (const float*)d_in[1];
  const float* query = (const float*)d_in[2];
  const int*   mask  = (const int*)d_in[3];
  const float* Wk = (const float*)d_in[4];
  const float* bk = (const float*)d_in[5];
  const float* Wv = (const float*)d_in[6];
  const float* bv = (const float*)d_in[7];
  const float* Wq = (const float*)d_in[8];
  const float* bq = (const float*)d_in[9];
  const float* Wo = (const float*)d_in[10];
  const float* bo = (const float*)d_in[11];

  char* ws = (char*)d_ws;
  const size_t MB = 1ull << 20;
  float*  kbuf = (float*)(ws + 0 * MB);     // 32 MB (8.4M floats)
  float*  vbuf = (float*)(ws + 34 * MB);    // 32 MB
  float*  qbuf = (float*)(ws + 68 * MB);    // 32 MB
  float*  ctxb = (float*)(ws + 102 * MB);   // 32 MB
  u64*    pm   = (u64*)(ws + 136 * MB);     // 2 MB
  float2* stat = (float2*)(ws + 139 * MB);  // 1 MB

  float* out     = (float*)d_out;
  float* topattn = out + (size_t)Bn * Ln * Dn;

  const int M = Bn * Ln;   // 8192

  gemm_f32<<<dim3(Dn / 64, M / 64), 256, 0, stream>>>(key,   Wk, bk, kbuf, M, Dn, Dn, 1.0f);
  gemm_f32<<<dim3(Dn / 64, M / 64), 256, 0, stream>>>(value, Wv, bv, vbuf, M, Dn, Dn, 1.0f);
  gemm_f32<<<dim3(Dn / 64, M / 64), 256, 0, stream>>>(query, Wq, bq, qbuf, M, Dn, Dn, 0.125f);

  pack_mask<<<dim3((Bn * Ln * Ln) / 256), 256, 0, stream>>>(mask, pm);

  attn_stat<<<dim3(Ln / 32, Hn, Bn), 256, 0, stream>>>(qbuf, kbuf, pm, stat);
  attn_out<<<dim3(Ln / 32, Hn, Bn), 256, 0, stream>>>(qbuf, kbuf, vbuf, pm, stat, ctxb, topattn);

  gemm_f32<<<dim3(Dn / 64, M / 64), 256, 0, stream>>>(ctxb, Wo, bo, out, M, Dn, Dn, 1.0f);
}

// Round 5
// 3924.675 us; speedup vs baseline: 7.5489x; 7.5489x over previous
//
#include <hip/hip_runtime.h>
#include <hip/hip_bf16.h>
#include <stdint.h>

#define Bn 4
#define Ln 2048
#define Dn 1024
#define Hn 16
#define DHn 64

typedef __attribute__((ext_vector_type(8))) short short8;
typedef __attribute__((ext_vector_type(4))) float f32x4;
typedef unsigned long long u64;
typedef __hip_bfloat16 bf16;

__device__ __forceinline__ short f2b(float x) {
  bf16 b = __float2bfloat16(x);
  return *(short*)&b;
}

// ---------------- f32 -> bf16 elementwise (4 el / thread) ----------------
__global__ __launch_bounds__(256) void f32_to_bf16(const float* __restrict__ in,
                                                   short* __restrict__ out, int n4)
{
  int i = blockIdx.x * 256 + threadIdx.x;
  if (i < n4) {
    float4 v = ((const float4*)in)[i];
    short4 o;
    o.x = f2b(v.x); o.y = f2b(v.y); o.z = f2b(v.z); o.w = f2b(v.w);
    ((short4*)out)[i] = o;
  }
}

// ---------------- transpose + convert weight: WT_bf16[n][k] = W_f32[k][n] ----------------
__global__ __launch_bounds__(256) void transpose_w_bf16(
    const float* __restrict__ W0, const float* __restrict__ W1,
    const float* __restrict__ W2, const float* __restrict__ W3,
    short* __restrict__ WT0, short* __restrict__ WT1,
    short* __restrict__ WT2, short* __restrict__ WT3)
{
  __shared__ float t[64][65];
  const int z = blockIdx.z;
  const float* src = (z == 0) ? W0 : (z == 1) ? W1 : (z == 2) ? W2 : W3;
  short* dst = (z == 0) ? WT0 : (z == 1) ? WT1 : (z == 2) ? WT2 : WT3;
  const int tid = threadIdx.x;
  const int k0 = blockIdx.x * 64, n0 = blockIdx.y * 64;
  #pragma unroll
  for (int it = 0; it < 4; ++it) {
    int idx = it * 256 + tid;            // 0..1023 float4 slots
    int row = idx >> 4, c4 = (idx & 15) * 4;
    *(float4*)&t[row][c4] = *(const float4*)&src[(size_t)(k0 + row) * Dn + n0 + c4];
  }
  __syncthreads();
  #pragma unroll
  for (int it = 0; it < 4; ++it) {
    int idx = it * 256 + tid;            // short4 slots
    int nr = idx >> 4, kc = (idx & 15) * 4;
    short4 o;
    o.x = f2b(t[kc + 0][nr]); o.y = f2b(t[kc + 1][nr]);
    o.z = f2b(t[kc + 2][nr]); o.w = f2b(t[kc + 3][nr]);
    *(short4*)&dst[(size_t)(n0 + nr) * Dn + k0 + kc] = o;
  }
}

// ---------------- bf16 MFMA GEMM: C_f32[M,N] = (X[M,K] @ WT[N,K]^T + bias[N]) * scale ----------
__global__ __launch_bounds__(256) void gemm_bias_bf16(
    const short* __restrict__ Xs, const short* __restrict__ WTs,
    const float* __restrict__ bias, float* __restrict__ C,
    int M, int N, int K, float scale)
{
  __shared__ short lds[2 * 128 * 32];
  short* ldsA = lds;
  short* ldsB = lds + 128 * 32;
  const int tid  = threadIdx.x;
  const int lane = tid & 63;
  const int wv   = tid >> 6;
  const int quad = lane >> 4;
  const int l16  = lane & 15;
  const int m0 = blockIdx.y * 128, n0 = blockIdx.x * 128;
  const int wm = (wv >> 1) * 64, wn = (wv & 1) * 64;

  f32x4 acc[4][4];
  #pragma unroll
  for (int i = 0; i < 4; ++i)
    #pragma unroll
    for (int j = 0; j < 4; ++j)
      acc[i][j] = (f32x4){0.f, 0.f, 0.f, 0.f};

  for (int k0 = 0; k0 < K; k0 += 32) {
    short8 va[2], vb[2];
    #pragma unroll
    for (int r = 0; r < 2; ++r) {
      int idx = r * 256 + tid;
      int row = idx >> 2, kc = idx & 3;
      va[r] = *(const short8*)(Xs  + (size_t)(m0 + row) * K + k0 + kc * 8);
      vb[r] = *(const short8*)(WTs + (size_t)(n0 + row) * K + k0 + kc * 8);
    }
    __syncthreads();
    #pragma unroll
    for (int r = 0; r < 2; ++r) {
      int idx = r * 256 + tid;
      *(short8*)(ldsA + idx * 8) = va[r];
      *(short8*)(ldsB + idx * 8) = vb[r];
    }
    __syncthreads();
    short8 af[4], bfr[4];
    #pragma unroll
    for (int i = 0; i < 4; ++i)
      af[i] = *(const short8*)(ldsA + (wm + i * 16 + l16) * 32 + quad * 8);
    #pragma unroll
    for (int j = 0; j < 4; ++j)
      bfr[j] = *(const short8*)(ldsB + (wn + j * 16 + l16) * 32 + quad * 8);
    #pragma unroll
    for (int i = 0; i < 4; ++i)
      #pragma unroll
      for (int j = 0; j < 4; ++j)
        acc[i][j] = __builtin_amdgcn_mfma_f32_16x16x32_bf16(af[i], bfr[j], acc[i][j], 0, 0, 0);
  }

  #pragma unroll
  for (int j = 0; j < 4; ++j) {
    int n = n0 + wn + j * 16 + l16;
    float bv = bias[n];
    #pragma unroll
    for (int i = 0; i < 4; ++i) {
      int mb = m0 + wm + i * 16 + quad * 4;
      #pragma unroll
      for (int r = 0; r < 4; ++r)
        C[(size_t)(mb + r) * N + n] = (acc[i][j][r] + bv) * scale;
    }
  }
}

// ---------------- pack mask bits ----------------
__global__ __launch_bounds__(256) void pack_mask(const int* __restrict__ mask, u64* __restrict__ pm)
{
  size_t tg = (size_t)blockIdx.x * 256 + threadIdx.x;
  int v = mask[tg];
  u64 bal = __ballot(v != 0);
  if ((threadIdx.x & 63) == 0) pm[tg >> 6] = bal;
}

// ---------------- pass A: stat[bh][q] = (rowmax m, 1/l) ----------------
__global__ __launch_bounds__(256) void attn_stat(
    const float* __restrict__ Qb, const float* __restrict__ Kb,
    const u64* __restrict__ pm, float2* __restrict__ stat)
{
  __shared__ float ldsK[128][65];
  const int t = threadIdx.x;
  const int q = t >> 3, g = t & 7;
  const int b = blockIdx.z, h = blockIdx.y, q0 = blockIdx.x * 32;

  const float* qrow = Qb + ((size_t)(b * Ln + q0 + q)) * Dn + h * DHn;
  float4 qreg[16];
  #pragma unroll
  for (int d4 = 0; d4 < 16; ++d4) qreg[d4] = *(const float4*)&qrow[d4 * 4];

  const u64* pmq = pm + ((size_t)(b * Ln + q0 + q)) * 32;
  float mt = -INFINITY, lt = 0.f;

  for (int k0 = 0; k0 < Ln; k0 += 128) {
    __syncthreads();
    #pragma unroll
    for (int jj = 0; jj < 8; ++jj) {
      int idx = jj * 256 + t;
      int row = idx >> 4, c4 = (idx & 15) * 4;
      *(float4*)&ldsK[row][c4] =
          *(const float4*)&Kb[((size_t)(b * Ln + k0 + row)) * Dn + h * DHn + c4];
    }
    __syncthreads();
    u64 w0 = pmq[k0 >> 6], w1 = pmq[(k0 >> 6) + 1];
    #pragma unroll
    for (int kk = 0; kk < 16; ++kk) {
      int k = kk * 8 + g;
      u64 w = (k & 64) ? w1 : w0;
      bool msk = (w >> (k & 63)) & 1ull;
      if (!msk) {
        float s = 0.f;
        #pragma unroll
        for (int d4 = 0; d4 < 16; ++d4) {
          float4 kv = *(float4*)&ldsK[k][d4 * 4];
          s = fmaf(qreg[d4].x, kv.x, s);
          s = fmaf(qreg[d4].y, kv.y, s);
          s = fmaf(qreg[d4].z, kv.z, s);
          s = fmaf(qreg[d4].w, kv.w, s);
        }
        if (s <= mt) {
          lt += __expf(s - mt);
        } else {
          lt = lt * __expf(mt - s) + 1.0f;
          mt = s;
        }
      }
    }
  }
  #pragma unroll
  for (int off = 1; off < 8; off <<= 1) {
    float om = __shfl_xor(mt, off, 64);
    float ol = __shfl_xor(lt, off, 64);
    float nm = fmaxf(mt, om);
    float t1 = (lt > 0.f) ? lt * __expf(mt - nm) : 0.f;
    float t2 = (ol > 0.f) ? ol * __expf(om - nm) : 0.f;
    mt = nm; lt = t1 + t2;
  }
  if (g == 0) {
    float rinv = (lt > 0.f) ? 1.0f / lt : 0.f;
    stat[((size_t)(b * Hn + h)) * Ln + q0 + q] = make_float2(mt, rinv);
  }
}

// ---------------- pass B (no-spill): p through LDS; thread owns 8 output dims ----------------
__global__ __launch_bounds__(256) void attn_out(
    const float* __restrict__ Qb, const float* __restrict__ Kb,
    const float* __restrict__ Vb, const u64* __restrict__ pm,
    const float2* __restrict__ stat, short* __restrict__ ctx_bf,
    float* __restrict__ topattn)
{
  __shared__ float ldsK[64][68];
  __shared__ float ldsV[64][68];
  __shared__ float pp[32][68];
  const int t = threadIdx.x;
  const int q = t >> 3, g = t & 7;
  const int b = blockIdx.z, h = blockIdx.y, q0 = blockIdx.x * 32;

  const float* qrow = Qb + ((size_t)(b * Ln + q0 + q)) * Dn + h * DHn;
  float4 qreg[16];
  #pragma unroll
  for (int d4 = 0; d4 < 16; ++d4) qreg[d4] = *(const float4*)&qrow[d4 * 4];

  const u64* pmq = pm + ((size_t)(b * Ln + q0 + q)) * 32;
  float2 st = stat[((size_t)(b * Hn + h)) * Ln + q0 + q];
  const float m = st.x, rinv = st.y;

  float O[8];
  #pragma unroll
  for (int d = 0; d < 8; ++d) O[d] = 0.f;

  for (int k0 = 0; k0 < Ln; k0 += 64) {
    __syncthreads();
    #pragma unroll
    for (int jj = 0; jj < 4; ++jj) {
      int idx = jj * 256 + t;
      int row = idx >> 4, c4 = (idx & 15) * 4;
      size_t gsrc = ((size_t)(b * Ln + k0 + row)) * Dn + h * DHn + c4;
      *(float4*)&ldsK[row][c4] = *(const float4*)&Kb[gsrc];
      *(float4*)&ldsV[row][c4] = *(const float4*)&Vb[gsrc];
    }
    __syncthreads();
    u64 w = pmq[k0 >> 6];
    if (k0 & 64) w >>= 0;   // word covers k0..k0+63 exactly (64-aligned chunks)
    #pragma unroll
    for (int kk = 0; kk < 8; ++kk) {
      int k = kk * 8 + g;
      bool msk = (w >> k) & 1ull;   // chunk is 64-aligned: bit index = k
      float p = 0.f;
      if (!msk) {
        float s = 0.f;
        #pragma unroll
        for (int d4 = 0; d4 < 16; ++d4) {
          float4 kv = *(float4*)&ldsK[k][d4 * 4];
          s = fmaf(qreg[d4].x, kv.x, s);
          s = fmaf(qreg[d4].y, kv.y, s);
          s = fmaf(qreg[d4].z, kv.z, s);
          s = fmaf(qreg[d4].w, kv.w, s);
        }
        p = __expf(s - m) * rinv;
      }
      pp[q][k] = p;
      if (h == 0)
        topattn[((size_t)(b * Ln + q0 + q)) * Ln + k0 + k] = p;
    }
    __syncthreads();
    #pragma unroll
    for (int k = 0; k < 64; ++k) {
      float pk = pp[q][k];
      float4 v0 = *(float4*)&ldsV[k][g * 8];
      float4 v1 = *(float4*)&ldsV[k][g * 8 + 4];
      O[0] = fmaf(pk, v0.x, O[0]); O[1] = fmaf(pk, v0.y, O[1]);
      O[2] = fmaf(pk, v0.z, O[2]); O[3] = fmaf(pk, v0.w, O[3]);
      O[4] = fmaf(pk, v1.x, O[4]); O[5] = fmaf(pk, v1.y, O[5]);
      O[6] = fmaf(pk, v1.z, O[6]); O[7] = fmaf(pk, v1.w, O[7]);
    }
  }
  short* crow = ctx_bf + ((size_t)(b * Ln + q0 + q)) * Dn + h * DHn + g * 8;
  short4 o0, o1;
  o0.x = f2b(O[0]); o0.y = f2b(O[1]); o0.z = f2b(O[2]); o0.w = f2b(O[3]);
  o1.x = f2b(O[4]); o1.y = f2b(O[5]); o1.z = f2b(O[6]); o1.w = f2b(O[7]);
  *(short4*)&crow[0] = o0;
  *(short4*)&crow[4] = o1;
}

extern "C" void kernel_launch(void* const* d_in, const int* in_sizes, int n_in,
                              void* d_out, int out_size, void* d_ws, size_t ws_size,
                              hipStream_t stream) {
  (void)in_sizes; (void)n_in; (void)out_size; (void)ws_size;
  const float* key   = (const float*)d_in[0];
  const float* value = (const float*)d_in[1];
  const float* query = (const float*)d_in[2];
  const int*   mask  = (const int*)d_in[3];
  const float* Wk = (const float*)d_in[4];
  const float* bk = (const float*)d_in[5];
  const float* Wv = (const float*)d_in[6];
  const float* bv = (const float*)d_in[7];
  const float* Wq = (const float*)d_in[8];
  const float* bq = (const float*)d_in[9];
  const float* Wo = (const float*)d_in[10];
  const float* bo = (const float*)d_in[11];

  char* ws = (char*)d_ws;
  const size_t MiB = 1ull << 20;
  // bf16 converted inputs (dead after their GEMM):
  short* kc  = (short*)(ws + 0 * MiB);      // 16 MiB
  short* vc  = (short*)(ws + 16 * MiB);     // 16 MiB
  short* qc  = (short*)(ws + 32 * MiB);     // 16 MiB
  short* WkT = (short*)(ws + 48 * MiB);     // 2 MiB each
  short* WvT = (short*)(ws + 50 * MiB);
  short* WqT = (short*)(ws + 52 * MiB);
  short* WoT = (short*)(ws + 54 * MiB);
  float* kbuf = (float*)(ws + 56 * MiB);    // 32 MiB each (fp32)
  float* vbuf = (float*)(ws + 88 * MiB);
  float* qbuf = (float*)(ws + 120 * MiB);
  // reuse dead regions:
  short*  ctx_bf = (short*)(ws + 0 * MiB);  // over kc (dead)
  u64*    pm     = (u64*)(ws + 16 * MiB);   // over vc (dead), 2 MiB
  float2* stat   = (float2*)(ws + 18 * MiB);// over vc (dead), 1 MiB

  float* out     = (float*)d_out;
  float* topattn = out + (size_t)Bn * Ln * Dn;

  const int M = Bn * Ln;          // 8192
  const int n4 = (M * Dn) / 4;    // float4 count per tensor

  f32_to_bf16<<<dim3(n4 / 256), 256, 0, stream>>>(key,   kc, n4);
  f32_to_bf16<<<dim3(n4 / 256), 256, 0, stream>>>(value, vc, n4);
  f32_to_bf16<<<dim3(n4 / 256), 256, 0, stream>>>(query, qc, n4);
  transpose_w_bf16<<<dim3(16, 16, 4), 256, 0, stream>>>(Wk, Wv, Wq, Wo, WkT, WvT, WqT, WoT);

  gemm_bias_bf16<<<dim3(8, 64), 256, 0, stream>>>(kc, WkT, bk, kbuf, M, Dn, Dn, 1.0f);
  gemm_bias_bf16<<<dim3(8, 64), 256, 0, stream>>>(vc, WvT, bv, vbuf, M, Dn, Dn, 1.0f);
  gemm_bias_bf16<<<dim3(8, 64), 256, 0, stream>>>(qc, WqT, bq, qbuf, M, Dn, Dn, 0.125f);

  pack_mask<<<dim3((Bn * Ln * Ln) / 256), 256, 0, stream>>>(mask, pm);

  attn_stat<<<dim3(Ln / 32, Hn, Bn), 256, 0, stream>>>(qbuf, kbuf, pm, stat);
  attn_out<<<dim3(Ln / 32, Hn, Bn), 256, 0, stream>>>(qbuf, kbuf, vbuf, pm, stat, ctx_bf, topattn);

  gemm_bias_bf16<<<dim3(8, 64), 256, 0, stream>>>(ctx_bf, WoT, bo, out, M, Dn, Dn, 1.0f);
}